// Round 1
// baseline (1025.475 us; speedup 1.0000x reference)
//
#include <hip/hip_runtime.h>

#define GRAPHS 128

// ---------------- CSR build (by dst), reused for both convs ----------------
__global__ void k_count(const int* __restrict__ dst, int* __restrict__ deg, int e) {
  int i = blockIdx.x * 256 + threadIdx.x;
  if (i < e) atomicAdd(&deg[dst[i]], 1);
}

__global__ void k_scan1(const int* __restrict__ deg, int* __restrict__ bs, int n) {
  __shared__ int s[256];
  int t = threadIdx.x;
  int base = blockIdx.x * 1024 + t * 4;
  int sum = 0;
#pragma unroll
  for (int j = 0; j < 4; ++j) { int i = base + j; if (i < n) sum += deg[i]; }
  s[t] = sum; __syncthreads();
  for (int off = 128; off > 0; off >>= 1) {
    if (t < off) s[t] += s[t + off];
    __syncthreads();
  }
  if (t == 0) bs[blockIdx.x] = s[0];
}

__global__ void k_scan2(int* bs, int nb) {  // 1 block, nb <= 256
  __shared__ int s[256];
  int t = threadIdx.x;
  int v = (t < nb) ? bs[t] : 0;
  s[t] = v; __syncthreads();
  for (int off = 1; off < 256; off <<= 1) {
    int x = (t >= off) ? s[t - off] : 0;
    __syncthreads();
    s[t] += x;
    __syncthreads();
  }
  if (t < nb) bs[t] = s[t] - v;  // exclusive block offsets
}

__global__ void k_scan3(const int* __restrict__ deg, const int* __restrict__ bs,
                        int* __restrict__ ptr, int* __restrict__ cur, int n, int e) {
  __shared__ int s[256];
  int t = threadIdx.x, b = blockIdx.x;
  int base = b * 1024 + t * 4;
  int v[4]; int tot = 0;
#pragma unroll
  for (int j = 0; j < 4; ++j) { int i = base + j; v[j] = (i < n) ? deg[i] : 0; tot += v[j]; }
  s[t] = tot; __syncthreads();
  for (int off = 1; off < 256; off <<= 1) {
    int x = (t >= off) ? s[t - off] : 0;
    __syncthreads();
    s[t] += x;
    __syncthreads();
  }
  int off = bs[b] + s[t] - tot;
#pragma unroll
  for (int j = 0; j < 4; ++j) {
    int i = base + j;
    if (i < n) { ptr[i] = off; cur[i] = off; off += v[j]; }
  }
  if (b == 0 && t == 0) ptr[n] = e;
}

__global__ void k_fill(const int* __restrict__ src, const int* __restrict__ dst,
                       int* __restrict__ cur, int* __restrict__ csr, int e) {
  int i = blockIdx.x * 256 + threadIdx.x;
  if (i < e) { int pos = atomicAdd(&cur[dst[i]], 1); csr[pos] = src[i]; }
}

// ------------- aggregation: out[i] = in[i] + sum_{j in N(i)} in[j] -------------
// one wave per node, 2 channels (float2) per lane
__global__ void k_agg(const float* __restrict__ in, float* __restrict__ out,
                      const int* __restrict__ ptr, const int* __restrict__ csr, int n) {
  int gid = blockIdx.x * 256 + threadIdx.x;
  int node = gid >> 6, lane = gid & 63;
  if (node >= n) return;
  const float2* inp = (const float2*)in;
  float2 acc = inp[(long)node * 64 + lane];
  int s = ptr[node], epos = ptr[node + 1];
  for (int idx = s; idx < epos; ++idx) {
    int j = csr[idx];  // lane-uniform -> broadcast
    float2 v = inp[(long)j * 64 + lane];
    acc.x += v.x; acc.y += v.y;
  }
  ((float2*)out)[(long)node * 64 + lane] = acc;
}

// ------------- fp32 GEMM: out = relu(in @ W + b), IN=128, OUT=128 -------------
// tile 128 rows x 128 ch, 512 threads, W^T in LDS pitch 132, micro 8x4
// NOTE: no __restrict__ on in/out: called in-place (safe: tile staged to LDS first)
__launch_bounds__(512)
__global__ void k_gemm128(const float* in, const float* __restrict__ W,
                          const float* __restrict__ bias, float* out, int n) {
  __shared__ float4 xs[128 * 32];   // 64 KB
  __shared__ float wt[128 * 132];   // 67.6 KB, wt[c][k]
  int t = threadIdx.x;
  int r0 = blockIdx.x * 128;
#pragma unroll
  for (int i = 0; i < 8; ++i) {
    int id = t + i * 512;           // 0..4095
    int row = id >> 5, k4 = id & 31;
    float4 v = make_float4(0.f, 0.f, 0.f, 0.f);
    if (r0 + row < n) v = ((const float4*)in)[(long)(r0 + row) * 32 + k4];
    xs[row * 32 + k4] = v;
  }
#pragma unroll
  for (int i = 0; i < 8; ++i) {
    int id = t + i * 512;
    int k = id >> 5, c4 = id & 31;
    float4 v = ((const float4*)W)[k * 32 + c4];
    wt[(c4 * 4 + 0) * 132 + k] = v.x;
    wt[(c4 * 4 + 1) * 132 + k] = v.y;
    wt[(c4 * 4 + 2) * 132 + k] = v.z;
    wt[(c4 * 4 + 3) * 132 + k] = v.w;
  }
  __syncthreads();
  int tc = t & 31, tr = t >> 5;     // 16 row-threads x 32 ch-threads
  float acc[8][4];
#pragma unroll
  for (int r = 0; r < 8; ++r)
#pragma unroll
    for (int c = 0; c < 4; ++c) acc[r][c] = 0.f;
  for (int k4 = 0; k4 < 32; ++k4) {
    float4 xv[8], wv[4];
#pragma unroll
    for (int r = 0; r < 8; ++r) xv[r] = xs[(tr * 8 + r) * 32 + k4];
#pragma unroll
    for (int c = 0; c < 4; ++c) wv[c] = *(const float4*)&wt[(c * 32 + tc) * 132 + k4 * 4];
#pragma unroll
    for (int r = 0; r < 8; ++r)
#pragma unroll
      for (int c = 0; c < 4; ++c)
        acc[r][c] += xv[r].x * wv[c].x + xv[r].y * wv[c].y +
                     xv[r].z * wv[c].z + xv[r].w * wv[c].w;
  }
#pragma unroll
  for (int c = 0; c < 4; ++c) {
    int ch = c * 32 + tc;
    float b = bias[ch];
#pragma unroll
    for (int r = 0; r < 8; ++r) {
      int row = r0 + tr * 8 + r;
      if (row < n) out[(long)row * 128 + ch] = fmaxf(acc[r][c] + b, 0.f);
    }
  }
}

// ------- final GEMM (OUT=256) fused with per-graph sum pooling (batch sorted) -------
__launch_bounds__(512)
__global__ void k_gemm256_pool(const float* __restrict__ in, const float* __restrict__ W,
                               const float* __restrict__ bias, const int* __restrict__ batch,
                               float* __restrict__ pool, int n) {
  __shared__ float4 xs[128 * 32];
  __shared__ float wt[128 * 132];
  int t = threadIdx.x;
  int r0 = blockIdx.x * 128;
#pragma unroll
  for (int i = 0; i < 8; ++i) {
    int id = t + i * 512;
    int row = id >> 5, k4 = id & 31;
    float4 v = make_float4(0.f, 0.f, 0.f, 0.f);
    if (r0 + row < n) v = ((const float4*)in)[(long)(r0 + row) * 32 + k4];
    xs[row * 32 + k4] = v;
  }
  int tc = t & 31, tr = t >> 5;
  int bg[8];
#pragma unroll
  for (int r = 0; r < 8; ++r) {
    int row = r0 + tr * 8 + r;
    bg[r] = (row < n) ? batch[row] : -1;
  }
  for (int h = 0; h < 2; ++h) {
    __syncthreads();  // covers xs at h=0; protects wt re-stage at h=1
#pragma unroll
    for (int i = 0; i < 8; ++i) {
      int id = t + i * 512;
      int k = id >> 5, c4 = id & 31;
      float4 v = ((const float4*)W)[k * 64 + h * 32 + c4];
      wt[(c4 * 4 + 0) * 132 + k] = v.x;
      wt[(c4 * 4 + 1) * 132 + k] = v.y;
      wt[(c4 * 4 + 2) * 132 + k] = v.z;
      wt[(c4 * 4 + 3) * 132 + k] = v.w;
    }
    __syncthreads();
    float acc[8][4];
#pragma unroll
    for (int r = 0; r < 8; ++r)
#pragma unroll
      for (int c = 0; c < 4; ++c) acc[r][c] = 0.f;
    for (int k4 = 0; k4 < 32; ++k4) {
      float4 xv[8], wv[4];
#pragma unroll
      for (int r = 0; r < 8; ++r) xv[r] = xs[(tr * 8 + r) * 32 + k4];
#pragma unroll
      for (int c = 0; c < 4; ++c) wv[c] = *(const float4*)&wt[(c * 32 + tc) * 132 + k4 * 4];
#pragma unroll
      for (int r = 0; r < 8; ++r)
#pragma unroll
        for (int c = 0; c < 4; ++c)
          acc[r][c] += xv[r].x * wv[c].x + xv[r].y * wv[c].y +
                       xv[r].z * wv[c].z + xv[r].w * wv[c].w;
    }
#pragma unroll
    for (int c = 0; c < 4; ++c) {
      int ch = h * 128 + c * 32 + tc;
      float b = bias[ch];
      float run = 0.f; int curg = -1;
#pragma unroll
      for (int r = 0; r < 8; ++r) {
        if (bg[r] < 0) break;   // rows sorted; -1 only at the tail
        float v = fmaxf(acc[r][c] + b, 0.f);
        if (bg[r] != curg) {
          if (curg >= 0) atomicAdd(&pool[curg * 256 + ch], run);
          curg = bg[r]; run = 0.f;
        }
        run += v;
      }
      if (curg >= 0) atomicAdd(&pool[curg * 256 + ch], run);
    }
  }
}

// ---------------- graph boundaries + LayerNorm finalize ----------------
__global__ void k_starts(const int* __restrict__ batch, int* __restrict__ starts, int n) {
  int g = threadIdx.x;
  if (g > GRAPHS) return;
  int lo = 0, hi = n;
  while (lo < hi) { int mid = (lo + hi) >> 1; if (batch[mid] < g) lo = mid + 1; else hi = mid; }
  starts[g] = lo;
}

__global__ void k_final(const float* __restrict__ pool, const int* __restrict__ starts,
                        const float* __restrict__ gamma, const float* __restrict__ beta,
                        float* __restrict__ out) {
  __shared__ float2 red[256];
  int g = blockIdx.x, ch = threadIdx.x;
  int cnt = starts[g + 1] - starts[g];
  float p = pool[g * 256 + ch] / fmaxf((float)cnt, 1.f);
  red[ch] = make_float2(p, p * p);
  __syncthreads();
  for (int off = 128; off > 0; off >>= 1) {
    if (ch < off) { red[ch].x += red[ch + off].x; red[ch].y += red[ch + off].y; }
    __syncthreads();
  }
  float mu = red[0].x * (1.f / 256.f);
  float var = red[0].y * (1.f / 256.f) - mu * mu;
  out[g * 256 + ch] = (p - mu) * rsqrtf(var + 1e-5f) * gamma[ch] + beta[ch];
}

extern "C" void kernel_launch(void* const* d_in, const int* in_sizes, int n_in,
                              void* d_out, int out_size, void* d_ws, size_t ws_size,
                              hipStream_t stream) {
  const float* x     = (const float*)d_in[0];
  const int*   ei    = (const int*)d_in[1];
  const int*   batch = (const int*)d_in[2];
  const float* W11 = (const float*)d_in[3];  const float* b11 = (const float*)d_in[4];
  const float* W12 = (const float*)d_in[5];  const float* b12 = (const float*)d_in[6];
  const float* W21 = (const float*)d_in[7];  const float* b21 = (const float*)d_in[8];
  const float* W22 = (const float*)d_in[9];  const float* b22 = (const float*)d_in[10];
  const float* gamma = (const float*)d_in[11];
  const float* beta  = (const float*)d_in[12];
  float* out = (float*)d_out;

  int n = in_sizes[0] / 128;   // 100000
  int e = in_sizes[1] / 2;     // 1600000
  const int* src = ei;
  const int* dstv = ei + e;

  char* ws = (char*)d_ws;
  float* A    = (float*)ws; ws += (size_t)n * 128 * 4;
  float* B    = (float*)ws; ws += (size_t)n * 128 * 4;
  float* pool = (float*)ws; ws += (size_t)GRAPHS * 256 * 4;
  int* deg    = (int*)ws;   ws += (size_t)n * 4;
  int* ptr    = (int*)ws;   ws += (size_t)(n + 1) * 4;
  int* cur    = (int*)ws;   ws += (size_t)n * 4;
  int* csr    = (int*)ws;   ws += (size_t)e * 4;
  int* bs     = (int*)ws;   ws += 256 * 4;
  int* starts = (int*)ws;   ws += (GRAPHS + 1) * 4;

  hipMemsetAsync(deg, 0, (size_t)n * 4, stream);
  hipMemsetAsync(pool, 0, (size_t)GRAPHS * 256 * 4, stream);

  int nb = (n + 1023) / 1024;           // 98 blocks for the scan
  int eb = (e + 255) / 256;
  k_count<<<eb, 256, 0, stream>>>(dstv, deg, e);
  k_scan1<<<nb, 256, 0, stream>>>(deg, bs, n);
  k_scan2<<<1, 256, 0, stream>>>(bs, nb);
  k_scan3<<<nb, 256, 0, stream>>>(deg, bs, ptr, cur, n, e);
  k_fill<<<eb, 256, 0, stream>>>(src, dstv, cur, csr, e);
  k_starts<<<1, 256, 0, stream>>>(batch, starts, n);

  int gb = (n + 127) / 128;             // GEMM row tiles
  int ab = (n * 64 + 255) / 256;        // one wave per node

  k_agg<<<ab, 256, 0, stream>>>(x, A, ptr, csr, n);          // A = x + agg(x)
  k_gemm128<<<gb, 512, 0, stream>>>(A, W11, b11, A, n);      // A = relu(A@W11+b11)
  k_gemm128<<<gb, 512, 0, stream>>>(A, W12, b12, B, n);      // B = relu(A@W12+b12) = h1
  k_agg<<<ab, 256, 0, stream>>>(B, A, ptr, csr, n);          // A = h1 + agg(h1)
  k_gemm128<<<gb, 512, 0, stream>>>(A, W21, b21, A, n);      // A = relu(A@W21+b21)
  k_gemm256_pool<<<gb, 512, 0, stream>>>(A, W22, b22, batch, pool, n);
  k_final<<<GRAPHS, 256, 0, stream>>>(pool, starts, gamma, beta, out);
}

// Round 3
// 697.883 us; speedup vs baseline: 1.4694x; 1.4694x over previous
//
#include <hip/hip_runtime.h>

#define GRAPHS 128

typedef _Float16 f16x8 __attribute__((ext_vector_type(8)));
typedef _Float16 f16x4 __attribute__((ext_vector_type(4)));
typedef float f32x4 __attribute__((ext_vector_type(4)));

// ---------------- CSR build (by dst), reused for both convs ----------------
__global__ void k_count(const int* __restrict__ dst, int* __restrict__ deg, int e) {
  int i = blockIdx.x * 256 + threadIdx.x;
  if (i < e) atomicAdd(&deg[dst[i]], 1);
}

__global__ void k_scan1(const int* __restrict__ deg, int* __restrict__ bs, int n) {
  __shared__ int s[256];
  int t = threadIdx.x;
  int base = blockIdx.x * 1024 + t * 4;
  int sum = 0;
#pragma unroll
  for (int j = 0; j < 4; ++j) { int i = base + j; if (i < n) sum += deg[i]; }
  s[t] = sum; __syncthreads();
  for (int off = 128; off > 0; off >>= 1) {
    if (t < off) s[t] += s[t + off];
    __syncthreads();
  }
  if (t == 0) bs[blockIdx.x] = s[0];
}

__global__ void k_scan2(int* bs, int nb) {  // 1 block, nb <= 256
  __shared__ int s[256];
  int t = threadIdx.x;
  int v = (t < nb) ? bs[t] : 0;
  s[t] = v; __syncthreads();
  for (int off = 1; off < 256; off <<= 1) {
    int x = (t >= off) ? s[t - off] : 0;
    __syncthreads();
    s[t] += x;
    __syncthreads();
  }
  if (t < nb) bs[t] = s[t] - v;  // exclusive block offsets
}

__global__ void k_scan3(const int* __restrict__ deg, const int* __restrict__ bs,
                        int* __restrict__ ptr, int* __restrict__ cur, int n, int e) {
  __shared__ int s[256];
  int t = threadIdx.x, b = blockIdx.x;
  int base = b * 1024 + t * 4;
  int v[4]; int tot = 0;
#pragma unroll
  for (int j = 0; j < 4; ++j) { int i = base + j; v[j] = (i < n) ? deg[i] : 0; tot += v[j]; }
  s[t] = tot; __syncthreads();
  for (int off = 1; off < 256; off <<= 1) {
    int x = (t >= off) ? s[t - off] : 0;
    __syncthreads();
    s[t] += x;
    __syncthreads();
  }
  int off = bs[b] + s[t] - tot;
#pragma unroll
  for (int j = 0; j < 4; ++j) {
    int i = base + j;
    if (i < n) { ptr[i] = off; cur[i] = off; off += v[j]; }
  }
  if (b == 0 && t == 0) ptr[n] = e;
}

__global__ void k_fill(const int* __restrict__ src, const int* __restrict__ dst,
                       int* __restrict__ cur, int* __restrict__ csr, int e) {
  int i = blockIdx.x * 256 + threadIdx.x;
  if (i < e) { int pos = atomicAdd(&cur[dst[i]], 1); csr[pos] = src[i]; }
}

// ------------- aggregation: out[i] = in[i] + sum_{j in N(i)} in[j] -------------
__global__ void k_agg(const float* __restrict__ in, float* __restrict__ out,
                      const int* __restrict__ ptr, const int* __restrict__ csr, int n) {
  int gid = blockIdx.x * 256 + threadIdx.x;
  int node = gid >> 6, lane = gid & 63;
  if (node >= n) return;
  const float2* inp = (const float2*)in;
  float2 acc = inp[(long)node * 64 + lane];
  int s = ptr[node], epos = ptr[node + 1];
  for (int idx = s; idx < epos; ++idx) {
    int j = csr[idx];  // lane-uniform -> broadcast
    float2 v = inp[(long)j * 64 + lane];
    acc.x += v.x; acc.y += v.y;
  }
  ((float2*)out)[(long)node * 64 + lane] = acc;
}

// -------- weight prep: W[k][c] fp32 -> Wt[c][k] f16 (grid = C, 128 threads) --------
__global__ void k_wprep(const float* __restrict__ W, _Float16* __restrict__ Wt, int C) {
  int c = blockIdx.x, k = threadIdx.x;
  Wt[c * 128 + k] = (_Float16)W[k * C + c];
}

// ------------- MFMA f16 GEMM: out = relu(in @ W + b), 128 -> 128 -------------
// 256 threads (4 waves), 128-row tile, wave = 32 rows x 128 cols.
// xs/wt pitch 136 f16 (272 B) keeps b128 reads ~2-way-conflict-free & 16B aligned.
__launch_bounds__(256)
__global__ void k_gemm128_f16(const float* in, const _Float16* __restrict__ Wt,
                              const float* __restrict__ bias, float* out, int n) {
  __shared__ _Float16 xs[128 * 136];
  __shared__ _Float16 wt[128 * 136];
  int t = threadIdx.x;
  int r0 = blockIdx.x * 128;
#pragma unroll
  for (int i = 0; i < 16; ++i) {
    int id = t + i * 256;           // 0..4095
    int row = id >> 5, k4 = id & 31;
    float4 v = make_float4(0.f, 0.f, 0.f, 0.f);
    if (r0 + row < n) v = ((const float4*)in)[(size_t)(r0 + row) * 32 + k4];
    f16x4 hv = { (_Float16)v.x, (_Float16)v.y, (_Float16)v.z, (_Float16)v.w };
    *(f16x4*)&xs[row * 136 + k4 * 4] = hv;
  }
#pragma unroll
  for (int i = 0; i < 8; ++i) {
    int id = t + i * 256;           // 0..2047 = 128 cols x 16 chunks
    int c = id >> 4, k8 = id & 15;  // FIXED (was >>3 / &7: OOB + half-unwritten wt)
    *(f16x8*)&wt[c * 136 + k8 * 8] = ((const f16x8*)Wt)[c * 16 + k8];
  }
  __syncthreads();
  int lane = t & 63, w = t >> 6;
  int l16 = lane & 15, lk = (lane >> 4) * 8;
  int rw = w * 32;
  f32x4 acc[2][8];
#pragma unroll
  for (int fr = 0; fr < 2; ++fr)
#pragma unroll
    for (int fc = 0; fc < 8; ++fc) acc[fr][fc] = (f32x4){0.f, 0.f, 0.f, 0.f};
#pragma unroll
  for (int kk = 0; kk < 4; ++kk) {
    int klo = kk * 32 + lk;
    f16x8 a0 = *(const f16x8*)&xs[(rw + l16) * 136 + klo];
    f16x8 a1 = *(const f16x8*)&xs[(rw + 16 + l16) * 136 + klo];
#pragma unroll
    for (int fc = 0; fc < 8; ++fc) {
      f16x8 b = *(const f16x8*)&wt[(fc * 16 + l16) * 136 + klo];
      acc[0][fc] = __builtin_amdgcn_mfma_f32_16x16x32_f16(a0, b, acc[0][fc], 0, 0, 0);
      acc[1][fc] = __builtin_amdgcn_mfma_f32_16x16x32_f16(a1, b, acc[1][fc], 0, 0, 0);
    }
  }
  int rbase = r0 + rw + (lane >> 4) * 4;
#pragma unroll
  for (int fr = 0; fr < 2; ++fr)
#pragma unroll
    for (int fc = 0; fc < 8; ++fc) {
      int col = fc * 16 + l16;
      float bv = bias[col];
#pragma unroll
      for (int j = 0; j < 4; ++j) {
        int row = rbase + fr * 16 + j;
        if (row < n) out[(size_t)row * 128 + col] = fmaxf(acc[fr][fc][j] + bv, 0.f);
      }
    }
}

// ------- final GEMM 128 -> 256 (two 128-col chunks) fused with mean-pool sums -------
__launch_bounds__(256)
__global__ void k_gemm_pool_f16(const float* __restrict__ in, const _Float16* __restrict__ Wt,
                                const float* __restrict__ bias, const int* __restrict__ batch,
                                float* __restrict__ pool, int n) {
  __shared__ _Float16 xs[128 * 136];
  __shared__ _Float16 wt[128 * 136];
  __shared__ float pool_l[8 * 256];
  int t = threadIdx.x;
  int r0 = blockIdx.x * 128;
#pragma unroll
  for (int j = 0; j < 8; ++j) pool_l[j * 256 + t] = 0.f;
#pragma unroll
  for (int i = 0; i < 16; ++i) {
    int id = t + i * 256;
    int row = id >> 5, k4 = id & 31;
    float4 v = make_float4(0.f, 0.f, 0.f, 0.f);
    if (r0 + row < n) v = ((const float4*)in)[(size_t)(r0 + row) * 32 + k4];
    f16x4 hv = { (_Float16)v.x, (_Float16)v.y, (_Float16)v.z, (_Float16)v.w };
    *(f16x4*)&xs[row * 136 + k4 * 4] = hv;
  }
  int lane = t & 63, w = t >> 6;
  int l16 = lane & 15, lk = (lane >> 4) * 8;
  int rw = w * 32;
  int g0 = batch[r0];
  int g4[2][4];
  int rbase = r0 + rw + (lane >> 4) * 4;
#pragma unroll
  for (int fr = 0; fr < 2; ++fr)
#pragma unroll
    for (int j = 0; j < 4; ++j) {
      int row = rbase + fr * 16 + j;
      g4[fr][j] = (row < n) ? batch[row] : -1;
    }
  for (int h = 0; h < 2; ++h) {
    if (h) __syncthreads();             // all waves done reading chunk-0 wt
#pragma unroll
    for (int i = 0; i < 8; ++i) {
      int id = t + i * 256;             // 0..2047 = 128 cols x 16 chunks
      int c = id >> 4, k8 = id & 15;    // FIXED (was >>3 / &7)
      *(f16x8*)&wt[c * 136 + k8 * 8] = ((const f16x8*)Wt)[(h * 128 + c) * 16 + k8];
    }
    __syncthreads();
    f32x4 acc[2][8];
#pragma unroll
    for (int fr = 0; fr < 2; ++fr)
#pragma unroll
      for (int fc = 0; fc < 8; ++fc) acc[fr][fc] = (f32x4){0.f, 0.f, 0.f, 0.f};
#pragma unroll
    for (int kk = 0; kk < 4; ++kk) {
      int klo = kk * 32 + lk;
      f16x8 a0 = *(const f16x8*)&xs[(rw + l16) * 136 + klo];
      f16x8 a1 = *(const f16x8*)&xs[(rw + 16 + l16) * 136 + klo];
#pragma unroll
      for (int fc = 0; fc < 8; ++fc) {
        f16x8 b = *(const f16x8*)&wt[(fc * 16 + l16) * 136 + klo];
        acc[0][fc] = __builtin_amdgcn_mfma_f32_16x16x32_f16(a0, b, acc[0][fc], 0, 0, 0);
        acc[1][fc] = __builtin_amdgcn_mfma_f32_16x16x32_f16(a1, b, acc[1][fc], 0, 0, 0);
      }
    }
    // pooled epilogue: run-compress the 4 consecutive rows each lane holds
#pragma unroll
    for (int fc = 0; fc < 8; ++fc) {
      int col = h * 128 + fc * 16 + l16;
      float bv = bias[col];
#pragma unroll
      for (int fr = 0; fr < 2; ++fr) {
        f32x4 a = acc[fr][fc];
        float run = fmaxf(a[0] + bv, 0.f);
#pragma unroll
        for (int j = 1; j < 4; ++j) {
          float v = fmaxf(a[j] + bv, 0.f);
          if (g4[fr][j] == g4[fr][j - 1]) run += v;
          else {
            int g = g4[fr][j - 1];
            if (g >= 0) {
              int d = g - g0;
              if (d >= 0 && d < 8) atomicAdd(&pool_l[d * 256 + col], run);
              else atomicAdd(&pool[g * 256 + col], run);
            }
            run = v;
          }
        }
        int g = g4[fr][3];
        if (g >= 0) {
          int d = g - g0;
          if (d >= 0 && d < 8) atomicAdd(&pool_l[d * 256 + col], run);
          else atomicAdd(&pool[g * 256 + col], run);
        }
      }
    }
  }
  __syncthreads();
#pragma unroll
  for (int j = 0; j < 8; ++j) {
    int g = g0 + j;
    float v = pool_l[j * 256 + t];
    if (g < GRAPHS && v != 0.f) atomicAdd(&pool[g * 256 + t], v);
  }
}

// ---------------- graph boundaries + LayerNorm finalize ----------------
__global__ void k_starts(const int* __restrict__ batch, int* __restrict__ starts, int n) {
  int g = threadIdx.x;
  if (g > GRAPHS) return;
  int lo = 0, hi = n;
  while (lo < hi) { int mid = (lo + hi) >> 1; if (batch[mid] < g) lo = mid + 1; else hi = mid; }
  starts[g] = lo;
}

__global__ void k_final(const float* __restrict__ pool, const int* __restrict__ starts,
                        const float* __restrict__ gamma, const float* __restrict__ beta,
                        float* __restrict__ out) {
  __shared__ float2 red[256];
  int g = blockIdx.x, ch = threadIdx.x;
  int cnt = starts[g + 1] - starts[g];
  float p = pool[g * 256 + ch] / fmaxf((float)cnt, 1.f);
  red[ch] = make_float2(p, p * p);
  __syncthreads();
  for (int off = 128; off > 0; off >>= 1) {
    if (ch < off) { red[ch].x += red[ch + off].x; red[ch].y += red[ch + off].y; }
    __syncthreads();
  }
  float mu = red[0].x * (1.f / 256.f);
  float var = red[0].y * (1.f / 256.f) - mu * mu;
  out[g * 256 + ch] = (p - mu) * rsqrtf(var + 1e-5f) * gamma[ch] + beta[ch];
}

extern "C" void kernel_launch(void* const* d_in, const int* in_sizes, int n_in,
                              void* d_out, int out_size, void* d_ws, size_t ws_size,
                              hipStream_t stream) {
  const float* x     = (const float*)d_in[0];
  const int*   ei    = (const int*)d_in[1];
  const int*   batch = (const int*)d_in[2];
  const float* W11 = (const float*)d_in[3];  const float* b11 = (const float*)d_in[4];
  const float* W12 = (const float*)d_in[5];  const float* b12 = (const float*)d_in[6];
  const float* W21 = (const float*)d_in[7];  const float* b21 = (const float*)d_in[8];
  const float* W22 = (const float*)d_in[9];  const float* b22 = (const float*)d_in[10];
  const float* gamma = (const float*)d_in[11];
  const float* beta  = (const float*)d_in[12];
  float* out = (float*)d_out;

  int n = in_sizes[0] / 128;   // 100000
  int e = in_sizes[1] / 2;     // 1600000
  const int* src = ei;
  const int* dstv = ei + e;

  char* ws = (char*)d_ws;
  auto alloc = [&](size_t bytes) { char* p = ws; ws += (bytes + 15) & ~(size_t)15; return p; };
  float* A    = (float*)alloc((size_t)n * 128 * 4);
  float* B    = (float*)alloc((size_t)n * 128 * 4);
  float* pool = (float*)alloc((size_t)GRAPHS * 256 * 4);
  int* deg    = (int*)alloc((size_t)n * 4);
  int* ptr    = (int*)alloc((size_t)(n + 1) * 4);
  int* cur    = (int*)alloc((size_t)n * 4);
  int* csr    = (int*)alloc((size_t)e * 4);
  int* bs     = (int*)alloc(256 * 4);
  int* starts = (int*)alloc((GRAPHS + 1) * 4);
  _Float16* w11t = (_Float16*)alloc(128 * 128 * 2);
  _Float16* w12t = (_Float16*)alloc(128 * 128 * 2);
  _Float16* w21t = (_Float16*)alloc(128 * 128 * 2);
  _Float16* w22t = (_Float16*)alloc(256 * 128 * 2);

  hipMemsetAsync(deg, 0, (size_t)n * 4, stream);
  hipMemsetAsync(pool, 0, (size_t)GRAPHS * 256 * 4, stream);

  int nb = (n + 1023) / 1024;
  int eb = (e + 255) / 256;
  k_count<<<eb, 256, 0, stream>>>(dstv, deg, e);
  k_scan1<<<nb, 256, 0, stream>>>(deg, bs, n);
  k_scan2<<<1, 256, 0, stream>>>(bs, nb);
  k_scan3<<<nb, 256, 0, stream>>>(deg, bs, ptr, cur, n, e);
  k_fill<<<eb, 256, 0, stream>>>(src, dstv, cur, csr, e);
  k_starts<<<1, 256, 0, stream>>>(batch, starts, n);
  k_wprep<<<128, 128, 0, stream>>>(W11, w11t, 128);
  k_wprep<<<128, 128, 0, stream>>>(W12, w12t, 128);
  k_wprep<<<128, 128, 0, stream>>>(W21, w21t, 128);
  k_wprep<<<256, 128, 0, stream>>>(W22, w22t, 256);

  int gb = (n + 127) / 128;
  int ab = (n * 64 + 255) / 256;

  k_agg<<<ab, 256, 0, stream>>>(x, A, ptr, csr, n);               // A = x + agg(x)
  k_gemm128_f16<<<gb, 256, 0, stream>>>(A, w11t, b11, A, n);      // A = relu(A@W11+b11)
  k_gemm128_f16<<<gb, 256, 0, stream>>>(A, w12t, b12, B, n);      // B = h1
  k_agg<<<ab, 256, 0, stream>>>(B, A, ptr, csr, n);               // A = h1 + agg(h1)
  k_gemm128_f16<<<gb, 256, 0, stream>>>(A, w21t, b21, A, n);      // A = relu(A@W21+b21)
  k_gemm_pool_f16<<<gb, 256, 0, stream>>>(A, w22t, b22, batch, pool, n);
  k_final<<<GRAPHS, 256, 0, stream>>>(pool, starts, gamma, beta, out);
}

// Round 4
// 496.225 us; speedup vs baseline: 2.0666x; 1.4064x over previous
//
#include <hip/hip_runtime.h>

#define GRAPHS 128

typedef _Float16 f16x8 __attribute__((ext_vector_type(8)));
typedef _Float16 f16x4 __attribute__((ext_vector_type(4)));
typedef _Float16 f16x2 __attribute__((ext_vector_type(2)));
typedef float f32x4 __attribute__((ext_vector_type(4)));

// ---------------- CSR build (by dst), reused for both convs ----------------
__global__ void k_count(const int* __restrict__ dst, int* __restrict__ deg, int e) {
  int i = blockIdx.x * 256 + threadIdx.x;
  if (i < e) atomicAdd(&deg[dst[i]], 1);
}

__global__ void k_scan1(const int* __restrict__ deg, int* __restrict__ bs, int n) {
  __shared__ int s[256];
  int t = threadIdx.x;
  int base = blockIdx.x * 1024 + t * 4;
  int sum = 0;
#pragma unroll
  for (int j = 0; j < 4; ++j) { int i = base + j; if (i < n) sum += deg[i]; }
  s[t] = sum; __syncthreads();
  for (int off = 128; off > 0; off >>= 1) {
    if (t < off) s[t] += s[t + off];
    __syncthreads();
  }
  if (t == 0) bs[blockIdx.x] = s[0];
}

__global__ void k_scan2(int* bs, int nb) {  // 1 block, nb <= 256
  __shared__ int s[256];
  int t = threadIdx.x;
  int v = (t < nb) ? bs[t] : 0;
  s[t] = v; __syncthreads();
  for (int off = 1; off < 256; off <<= 1) {
    int x = (t >= off) ? s[t - off] : 0;
    __syncthreads();
    s[t] += x;
    __syncthreads();
  }
  if (t < nb) bs[t] = s[t] - v;  // exclusive block offsets
}

__global__ void k_scan3(const int* __restrict__ deg, const int* __restrict__ bs,
                        int* __restrict__ ptr, int* __restrict__ cur, int n, int e) {
  __shared__ int s[256];
  int t = threadIdx.x, b = blockIdx.x;
  int base = b * 1024 + t * 4;
  int v[4]; int tot = 0;
#pragma unroll
  for (int j = 0; j < 4; ++j) { int i = base + j; v[j] = (i < n) ? deg[i] : 0; tot += v[j]; }
  s[t] = tot; __syncthreads();
  for (int off = 1; off < 256; off <<= 1) {
    int x = (t >= off) ? s[t - off] : 0;
    __syncthreads();
    s[t] += x;
    __syncthreads();
  }
  int off = bs[b] + s[t] - tot;
#pragma unroll
  for (int j = 0; j < 4; ++j) {
    int i = base + j;
    if (i < n) { ptr[i] = off; cur[i] = off; off += v[j]; }
  }
  if (b == 0 && t == 0) ptr[n] = e;
}

__global__ void k_fill(const int* __restrict__ src, const int* __restrict__ dst,
                       int* __restrict__ cur, int* __restrict__ csr, int e) {
  int i = blockIdx.x * 256 + threadIdx.x;
  if (i < e) { int pos = atomicAdd(&cur[dst[i]], 1); csr[pos] = src[i]; }
}

// ---------------- fp32 -> f16 conversion (x only) ----------------
__global__ void k_cvt(const float* __restrict__ in, _Float16* __restrict__ out, int total4) {
  int i = blockIdx.x * 256 + threadIdx.x;
  if (i >= total4) return;
  float4 v = ((const float4*)in)[i];
  f16x4 h = { (_Float16)v.x, (_Float16)v.y, (_Float16)v.z, (_Float16)v.w };
  ((f16x4*)out)[i] = h;
}

// ------------- aggregation (f16 in/out, fp32 accum): out[i] = in[i] + sum_N in[j] -------------
// one wave per node, 2 channels per lane; 4x-unrolled independent loads for MLP
__global__ void k_agg_h(const _Float16* __restrict__ in, _Float16* __restrict__ out,
                        const int* __restrict__ ptr, const int* __restrict__ csr, int n) {
  int gid = blockIdx.x * 256 + threadIdx.x;
  int node = gid >> 6, lane = gid & 63;
  if (node >= n) return;
  const f16x2* inp = (const f16x2*)in;
  f16x2 v = inp[(size_t)node * 64 + lane];
  float ax = (float)v[0], ay = (float)v[1];
  float bx = 0.f, by = 0.f, cx = 0.f, cy = 0.f, dx = 0.f, dy = 0.f;
  int s = ptr[node], e2 = ptr[node + 1];
  int idx = s;
  for (; idx + 4 <= e2; idx += 4) {
    int j0 = csr[idx], j1 = csr[idx + 1], j2 = csr[idx + 2], j3 = csr[idx + 3];
    f16x2 v0 = inp[(size_t)j0 * 64 + lane];
    f16x2 v1 = inp[(size_t)j1 * 64 + lane];
    f16x2 v2 = inp[(size_t)j2 * 64 + lane];
    f16x2 v3 = inp[(size_t)j3 * 64 + lane];
    ax += (float)v0[0]; ay += (float)v0[1];
    bx += (float)v1[0]; by += (float)v1[1];
    cx += (float)v2[0]; cy += (float)v2[1];
    dx += (float)v3[0]; dy += (float)v3[1];
  }
  for (; idx < e2; ++idx) {
    int j = csr[idx];
    f16x2 v0 = inp[(size_t)j * 64 + lane];
    ax += (float)v0[0]; ay += (float)v0[1];
  }
  float rx = (ax + bx) + (cx + dx), ry = (ay + by) + (cy + dy);
  f16x2 r = { (_Float16)rx, (_Float16)ry };
  ((f16x2*)out)[(size_t)node * 64 + lane] = r;
}

// -------- weight prep: W[k][c] fp32 -> Wt[c][k] f16 (grid = C, 128 threads) --------
__global__ void k_wprep(const float* __restrict__ W, _Float16* __restrict__ Wt, int C) {
  int c = blockIdx.x, k = threadIdx.x;
  Wt[c * 128 + k] = (_Float16)W[k * C + c];
}

// ------------- MFMA f16 GEMM: out = relu(in @ W + b), 128 -> 128, f16 in/out -------------
// 256 threads (4 waves), 128-row tile, wave = 32 rows x 128 cols. LDS pitch 136 f16.
__launch_bounds__(256)
__global__ void k_gemm128_f16(const _Float16* __restrict__ in, const _Float16* __restrict__ Wt,
                              const float* __restrict__ bias, _Float16* __restrict__ out, int n) {
  __shared__ _Float16 xs[128 * 136];
  __shared__ _Float16 wt[128 * 136];
  int t = threadIdx.x;
  int r0 = blockIdx.x * 128;
#pragma unroll
  for (int i = 0; i < 8; ++i) {
    int id = t + i * 256;           // 0..2047 = 128 rows x 16 chunks
    int row = id >> 4, k8 = id & 15;
    f16x8 v = {0, 0, 0, 0, 0, 0, 0, 0};
    if (r0 + row < n) v = ((const f16x8*)in)[(size_t)(r0 + row) * 16 + k8];
    *(f16x8*)&xs[row * 136 + k8 * 8] = v;
  }
#pragma unroll
  for (int i = 0; i < 8; ++i) {
    int id = t + i * 256;           // 0..2047 = 128 cols x 16 chunks
    int c = id >> 4, k8 = id & 15;
    *(f16x8*)&wt[c * 136 + k8 * 8] = ((const f16x8*)Wt)[c * 16 + k8];
  }
  __syncthreads();
  int lane = t & 63, w = t >> 6;
  int l16 = lane & 15, lk = (lane >> 4) * 8;
  int rw = w * 32;
  f32x4 acc[2][8];
#pragma unroll
  for (int fr = 0; fr < 2; ++fr)
#pragma unroll
    for (int fc = 0; fc < 8; ++fc) acc[fr][fc] = (f32x4){0.f, 0.f, 0.f, 0.f};
#pragma unroll
  for (int kk = 0; kk < 4; ++kk) {
    int klo = kk * 32 + lk;
    f16x8 a0 = *(const f16x8*)&xs[(rw + l16) * 136 + klo];
    f16x8 a1 = *(const f16x8*)&xs[(rw + 16 + l16) * 136 + klo];
#pragma unroll
    for (int fc = 0; fc < 8; ++fc) {
      f16x8 b = *(const f16x8*)&wt[(fc * 16 + l16) * 136 + klo];
      acc[0][fc] = __builtin_amdgcn_mfma_f32_16x16x32_f16(a0, b, acc[0][fc], 0, 0, 0);
      acc[1][fc] = __builtin_amdgcn_mfma_f32_16x16x32_f16(a1, b, acc[1][fc], 0, 0, 0);
    }
  }
  int rbase = r0 + rw + (lane >> 4) * 4;
#pragma unroll
  for (int fr = 0; fr < 2; ++fr)
#pragma unroll
    for (int fc = 0; fc < 8; ++fc) {
      int col = fc * 16 + l16;
      float bv = bias[col];
#pragma unroll
      for (int j = 0; j < 4; ++j) {
        int row = rbase + fr * 16 + j;
        if (row < n) out[(size_t)row * 128 + col] = (_Float16)fmaxf(acc[fr][fc][j] + bv, 0.f);
      }
    }
}

// ------- final GEMM 128 -> 256 (two 128-col chunks) fused with mean-pool sums -------
__launch_bounds__(256)
__global__ void k_gemm_pool_f16(const _Float16* __restrict__ in, const _Float16* __restrict__ Wt,
                                const float* __restrict__ bias, const int* __restrict__ batch,
                                float* __restrict__ pool, int n) {
  __shared__ _Float16 xs[128 * 136];
  __shared__ _Float16 wt[128 * 136];
  __shared__ float pool_l[8 * 256];
  int t = threadIdx.x;
  int r0 = blockIdx.x * 128;
#pragma unroll
  for (int j = 0; j < 8; ++j) pool_l[j * 256 + t] = 0.f;
#pragma unroll
  for (int i = 0; i < 8; ++i) {
    int id = t + i * 256;
    int row = id >> 4, k8 = id & 15;
    f16x8 v = {0, 0, 0, 0, 0, 0, 0, 0};
    if (r0 + row < n) v = ((const f16x8*)in)[(size_t)(r0 + row) * 16 + k8];
    *(f16x8*)&xs[row * 136 + k8 * 8] = v;
  }
  int lane = t & 63, w = t >> 6;
  int l16 = lane & 15, lk = (lane >> 4) * 8;
  int rw = w * 32;
  int g0 = batch[r0];
  int g4[2][4];
  int rbase = r0 + rw + (lane >> 4) * 4;
#pragma unroll
  for (int fr = 0; fr < 2; ++fr)
#pragma unroll
    for (int j = 0; j < 4; ++j) {
      int row = rbase + fr * 16 + j;
      g4[fr][j] = (row < n) ? batch[row] : -1;
    }
  for (int h = 0; h < 2; ++h) {
    if (h) __syncthreads();             // all waves done reading chunk-0 wt
#pragma unroll
    for (int i = 0; i < 8; ++i) {
      int id = t + i * 256;             // 0..2047 = 128 cols x 16 chunks
      int c = id >> 4, k8 = id & 15;
      *(f16x8*)&wt[c * 136 + k8 * 8] = ((const f16x8*)Wt)[(h * 128 + c) * 16 + k8];
    }
    __syncthreads();
    f32x4 acc[2][8];
#pragma unroll
    for (int fr = 0; fr < 2; ++fr)
#pragma unroll
      for (int fc = 0; fc < 8; ++fc) acc[fr][fc] = (f32x4){0.f, 0.f, 0.f, 0.f};
#pragma unroll
    for (int kk = 0; kk < 4; ++kk) {
      int klo = kk * 32 + lk;
      f16x8 a0 = *(const f16x8*)&xs[(rw + l16) * 136 + klo];
      f16x8 a1 = *(const f16x8*)&xs[(rw + 16 + l16) * 136 + klo];
#pragma unroll
      for (int fc = 0; fc < 8; ++fc) {
        f16x8 b = *(const f16x8*)&wt[(fc * 16 + l16) * 136 + klo];
        acc[0][fc] = __builtin_amdgcn_mfma_f32_16x16x32_f16(a0, b, acc[0][fc], 0, 0, 0);
        acc[1][fc] = __builtin_amdgcn_mfma_f32_16x16x32_f16(a1, b, acc[1][fc], 0, 0, 0);
      }
    }
    // pooled epilogue: run-compress the 4 consecutive rows each lane holds
#pragma unroll
    for (int fc = 0; fc < 8; ++fc) {
      int col = h * 128 + fc * 16 + l16;
      float bv = bias[col];
#pragma unroll
      for (int fr = 0; fr < 2; ++fr) {
        f32x4 a = acc[fr][fc];
        float run = fmaxf(a[0] + bv, 0.f);
#pragma unroll
        for (int j = 1; j < 4; ++j) {
          float v = fmaxf(a[j] + bv, 0.f);
          if (g4[fr][j] == g4[fr][j - 1]) run += v;
          else {
            int g = g4[fr][j - 1];
            if (g >= 0) {
              int d = g - g0;
              if (d >= 0 && d < 8) atomicAdd(&pool_l[d * 256 + col], run);
              else atomicAdd(&pool[g * 256 + col], run);
            }
            run = v;
          }
        }
        int g = g4[fr][3];
        if (g >= 0) {
          int d = g - g0;
          if (d >= 0 && d < 8) atomicAdd(&pool_l[d * 256 + col], run);
          else atomicAdd(&pool[g * 256 + col], run);
        }
      }
    }
  }
  __syncthreads();
#pragma unroll
  for (int j = 0; j < 8; ++j) {
    int g = g0 + j;
    float v = pool_l[j * 256 + t];
    if (g < GRAPHS && v != 0.f) atomicAdd(&pool[g * 256 + t], v);
  }
}

// ---------------- graph boundaries + LayerNorm finalize ----------------
__global__ void k_starts(const int* __restrict__ batch, int* __restrict__ starts, int n) {
  int g = threadIdx.x;
  if (g > GRAPHS) return;
  int lo = 0, hi = n;
  while (lo < hi) { int mid = (lo + hi) >> 1; if (batch[mid] < g) lo = mid + 1; else hi = mid; }
  starts[g] = lo;
}

__global__ void k_final(const float* __restrict__ pool, const int* __restrict__ starts,
                        const float* __restrict__ gamma, const float* __restrict__ beta,
                        float* __restrict__ out) {
  __shared__ float2 red[256];
  int g = blockIdx.x, ch = threadIdx.x;
  int cnt = starts[g + 1] - starts[g];
  float p = pool[g * 256 + ch] / fmaxf((float)cnt, 1.f);
  red[ch] = make_float2(p, p * p);
  __syncthreads();
  for (int off = 128; off > 0; off >>= 1) {
    if (ch < off) { red[ch].x += red[ch + off].x; red[ch].y += red[ch + off].y; }
    __syncthreads();
  }
  float mu = red[0].x * (1.f / 256.f);
  float var = red[0].y * (1.f / 256.f) - mu * mu;
  out[g * 256 + ch] = (p - mu) * rsqrtf(var + 1e-5f) * gamma[ch] + beta[ch];
}

extern "C" void kernel_launch(void* const* d_in, const int* in_sizes, int n_in,
                              void* d_out, int out_size, void* d_ws, size_t ws_size,
                              hipStream_t stream) {
  const float* x     = (const float*)d_in[0];
  const int*   ei    = (const int*)d_in[1];
  const int*   batch = (const int*)d_in[2];
  const float* W11 = (const float*)d_in[3];  const float* b11 = (const float*)d_in[4];
  const float* W12 = (const float*)d_in[5];  const float* b12 = (const float*)d_in[6];
  const float* W21 = (const float*)d_in[7];  const float* b21 = (const float*)d_in[8];
  const float* W22 = (const float*)d_in[9];  const float* b22 = (const float*)d_in[10];
  const float* gamma = (const float*)d_in[11];
  const float* beta  = (const float*)d_in[12];
  float* out = (float*)d_out;

  int n = in_sizes[0] / 128;   // 100000
  int e = in_sizes[1] / 2;     // 1600000
  const int* src = ei;
  const int* dstv = ei + e;

  char* ws = (char*)d_ws;
  auto alloc = [&](size_t bytes) { char* p = ws; ws += (bytes + 15) & ~(size_t)15; return p; };
  _Float16* P0 = (_Float16*)alloc((size_t)n * 128 * 2);
  _Float16* P1 = (_Float16*)alloc((size_t)n * 128 * 2);
  _Float16* P2 = (_Float16*)alloc((size_t)n * 128 * 2);
  float* pool = (float*)alloc((size_t)GRAPHS * 256 * 4);
  int* deg    = (int*)alloc((size_t)n * 4);
  int* ptr    = (int*)alloc((size_t)(n + 1) * 4);
  int* cur    = (int*)alloc((size_t)n * 4);
  int* csr    = (int*)alloc((size_t)e * 4);
  int* bs     = (int*)alloc(256 * 4);
  int* starts = (int*)alloc((GRAPHS + 1) * 4);
  _Float16* w11t = (_Float16*)alloc(128 * 128 * 2);
  _Float16* w12t = (_Float16*)alloc(128 * 128 * 2);
  _Float16* w21t = (_Float16*)alloc(128 * 128 * 2);
  _Float16* w22t = (_Float16*)alloc(256 * 128 * 2);

  hipMemsetAsync(deg, 0, (size_t)n * 4, stream);
  hipMemsetAsync(pool, 0, (size_t)GRAPHS * 256 * 4, stream);

  int nb = (n + 1023) / 1024;
  int eb = (e + 255) / 256;
  k_count<<<eb, 256, 0, stream>>>(dstv, deg, e);
  k_scan1<<<nb, 256, 0, stream>>>(deg, bs, n);
  k_scan2<<<1, 256, 0, stream>>>(bs, nb);
  k_scan3<<<nb, 256, 0, stream>>>(deg, bs, ptr, cur, n, e);
  k_fill<<<eb, 256, 0, stream>>>(src, dstv, cur, csr, e);
  k_starts<<<1, 256, 0, stream>>>(batch, starts, n);
  k_wprep<<<128, 128, 0, stream>>>(W11, w11t, 128);
  k_wprep<<<128, 128, 0, stream>>>(W12, w12t, 128);
  k_wprep<<<128, 128, 0, stream>>>(W21, w21t, 128);
  k_wprep<<<256, 128, 0, stream>>>(W22, w22t, 256);
  k_cvt<<<(n * 32 + 255) / 256, 256, 0, stream>>>(x, P0, n * 32);

  int gb = (n + 127) / 128;
  int ab = (n * 64 + 255) / 256;

  k_agg_h<<<ab, 256, 0, stream>>>(P0, P1, ptr, csr, n);             // P1 = x + agg(x)
  k_gemm128_f16<<<gb, 256, 0, stream>>>(P1, w11t, b11, P2, n);      // P2 = relu(P1@W11+b11)
  k_gemm128_f16<<<gb, 256, 0, stream>>>(P2, w12t, b12, P0, n);      // P0 = h1
  k_agg_h<<<ab, 256, 0, stream>>>(P0, P1, ptr, csr, n);             // P1 = h1 + agg(h1)
  k_gemm128_f16<<<gb, 256, 0, stream>>>(P1, w21t, b21, P2, n);      // P2 = relu(P1@W21+b21)
  k_gemm_pool_f16<<<gb, 256, 0, stream>>>(P2, w22t, b22, batch, pool, n);
  k_final<<<GRAPHS, 256, 0, stream>>>(pool, starts, gamma, beta, out);
}